// Round 17
// baseline (455.610 us; speedup 1.0000x reference)
//
#include <hip/hip_runtime.h>
#include <stdint.h>

typedef int i32x4 __attribute__((ext_vector_type(4)));
typedef unsigned short u16x8 __attribute__((ext_vector_type(8)));

#define N_TOK 2048
#define HID   4096
#define INTER 11008
#define TWOI  22016
#define KT1   64     // HID/64   k-steps for gemm1
#define KT2   172    // INTER/64 k-steps for gemm2

#define GLD16(gp, lp) __builtin_amdgcn_global_load_lds( \
    (const __attribute__((address_space(1))) void*)(gp), \
    (__attribute__((address_space(3))) void*)(lp), 16, 0, 0)
#define BAR() __builtin_amdgcn_s_barrier()
#define WVM(n) asm volatile("s_waitcnt vmcnt(" #n ")" ::: "memory")
// rule #18: lgkmcnt asm must be followed by sched_barrier(0).
#define LGKM0() do { asm volatile("s_waitcnt lgkmcnt(0)" ::: "memory"); \
                     __builtin_amdgcn_sched_barrier(0); } while (0)

__device__ __forceinline__ unsigned short f2bf(float f) {
  uint32_t u = __float_as_uint(f);
  uint32_t r = (u + 0x7fffu + ((u >> 16) & 1u)) >> 16;
  return (unsigned short)r;
}

__device__ __forceinline__ float bf2f(unsigned short b) {
  return __uint_as_float(((uint32_t)b) << 16);
}

// ---------------------------------------------------------------------------
// Pack int32 [R][K] -> int8 per-block panels [R/PR][K/64][PR][64]; four 16B
// units per 64B row permuted q' = q ^ (rl&3); GEMM reads at slot
// ((lane>>4)^(r15&3)) -> de-permuted + bank-spread.
// ---------------------------------------------------------------------------
__global__ __launch_bounds__(256) void pack_panel3(
    const int* __restrict__ src, uint8_t* __restrict__ dst,
    int lgPR, int KT, int K)
{
  const int u = blockIdx.x * 256 + threadIdx.x;
  const int q = u & 3;
  const int r2 = u >> 2;
  const int rl = r2 & ((1 << lgPR) - 1);
  const int s = r2 >> lgPR;
  const int p = s / KT;
  const int t = s - p * KT;
  const int row = (p << lgPR) + rl;
  const int col = t * 64 + ((q ^ (rl & 3)) << 4);
  const int* sp = src + (size_t)row * K + col;
  i32x4 o;
#pragma unroll
  for (int qq = 0; qq < 4; ++qq) {
    i32x4 w = *reinterpret_cast<const i32x4*>(sp + qq * 4);
    o[qq] = (w[0] & 255) | ((w[1] & 255) << 8) | ((w[2] & 255) << 16)
          | ((w[3] & 255) << 24);
  }
  *reinterpret_cast<i32x4*>(dst + (size_t)u * 16) = o;
}

// ---------------------------------------------------------------------------
// pack_gateup: panel nt pairs gate rows [nt*128..+128) with up rows
// [INTER+nt*128..+128): panel-row rl<128 -> gate, rl>=128 -> up.
// ---------------------------------------------------------------------------
__global__ __launch_bounds__(256) void pack_gateup(
    const int* __restrict__ src, uint8_t* __restrict__ dst)
{
  const int u = blockIdx.x * 256 + threadIdx.x;
  const int q = u & 3;
  const int r2 = u >> 2;
  const int rl = r2 & 255;
  const int s = r2 >> 8;
  const int p = s / KT1;
  const int t = s - p * KT1;
  const int srow = (rl < 128) ? (p * 128 + rl) : (INTER + p * 128 + rl - 128);
  const int col = t * 64 + ((q ^ (rl & 3)) << 4);
  const int* sp = src + (size_t)srow * HID + col;
  i32x4 o;
#pragma unroll
  for (int qq = 0; qq < 4; ++qq) {
    i32x4 w = *reinterpret_cast<const i32x4*>(sp + qq * 4);
    o[qq] = (w[0] & 255) | ((w[1] & 255) << 8) | ((w[2] & 255) << 16)
          | ((w[3] & 255) << 24);
  }
  *reinterpret_cast<i32x4*>(dst + (size_t)u * 16) = o;
}

__global__ __launch_bounds__(1024) void zero_mx(float* __restrict__ mx) {
  const int i = blockIdx.x * 1024 + threadIdx.x;
  if (i < N_TOK) mx[i] = 0.0f;
}

// ---------------------------------------------------------------------------
// GEMM1: 256x256 tile, 8 waves (2Mx4N, wave tile 128x64), BK=64B, 4-slot
// 32KB ring (128KB LDS), distance-3, counted vmcnt 8/4/0 — K-step now split
// into FOUR phases (T3 fine interleave on the race-free ring):
//   ph1 {bv4+av01 | stage Bg | bar lgkm0 | 8 MFMA}
//   ph2 {av23     | stage Bu | bar lgkm0 | 8 MFMA}
//   ph3 {av45     | stage Al | bar lgkm0 | 8 MFMA}
//   ph4 {av67     | stage Ah + vmcnt | bar lgkm0 | 8 MFMA}
// Epilogue: fused silu(gate)*up -> act bf16 + per-row atomicMax (r16).
// ---------------------------------------------------------------------------
__global__ __launch_bounds__(512, 2) void gemm1_k(
    const uint8_t* __restrict__ x8p, const uint8_t* __restrict__ wgp,
    const float* __restrict__ xs, const float* __restrict__ wgs,
    unsigned short* __restrict__ act, float* __restrict__ mx)
{
  __shared__ uint8_t sm[131072];         // 4 slots x (A 16KB + B 16KB)
  const int tid = threadIdx.x;
  const int lane = tid & 63, wid = tid >> 6;
  const int wgm = wid >> 2, wgn = wid & 3;
  const int r15 = lane & 15;
  const int slotC = (((lane >> 4) ^ (r15 & 3)) << 4);

  const int bid = blockIdx.x;
  const int v = (bid & 7) * 86 + (bid >> 3);   // 688 = 8*86, bijective
  const int mt = v & 7;                        // 8 M-tiles of 256
  const int ntB = v >> 3;                      // 86 paired col-tiles

  const uint8_t* pA = x8p + (size_t)mt  * (KT1 * 16384) + tid * 16;
  const uint8_t* pB = wgp + (size_t)ntB * (KT1 * 16384) + tid * 16;

  const int arow = (wgm << 7) + r15;           // 128-row wave stripe
  const int brow = (wgn << 6) + r15;
  i32x4 acc[8][4] = {};

#define RDA(dst, mi) dst = *reinterpret_cast<const i32x4*>( \
      b + (arow + (mi) * 16) * 64 + slotC)
#define MM8(m0) do {                                                 \
    __builtin_amdgcn_s_setprio(1);                                   \
    _Pragma("unroll")                                                \
    for (int n = 0; n < 4; ++n)                                      \
      acc[m0][n] = __builtin_amdgcn_mfma_i32_16x16x64_i8(            \
          avp[0], bv[n], acc[m0][n], 0, 0, 0);                       \
    _Pragma("unroll")                                                \
    for (int n = 0; n < 4; ++n)                                      \
      acc[(m0) + 1][n] = __builtin_amdgcn_mfma_i32_16x16x64_i8(      \
          avp[1], bv[n], acc[(m0) + 1][n], 0, 0, 0);                 \
    __builtin_amdgcn_s_setprio(0);                                   \
  } while (0)

  // prologue: stage tiles 0,1,2 (12 loads)
  {
    uint8_t* l0 = sm + 0 * 32768 + tid * 16;
    uint8_t* l1 = sm + 1 * 32768 + tid * 16;
    uint8_t* l2 = sm + 2 * 32768 + tid * 16;
    const uint8_t *aa, *bb;
    aa = pA; bb = pB;
    GLD16(aa, l0); GLD16(aa + 8192, l0 + 8192);
    GLD16(bb, l0 + 16384); GLD16(bb + 8192, l0 + 24576);
    aa = pA + 16384; bb = pB + 16384;
    GLD16(aa, l1); GLD16(aa + 8192, l1 + 8192);
    GLD16(bb, l1 + 16384); GLD16(bb + 8192, l1 + 24576);
    aa = pA + 32768; bb = pB + 32768;
    GLD16(aa, l2); GLD16(aa + 8192, l2 + 8192);
    GLD16(bb, l2 + 16384); GLD16(bb + 8192, l2 + 24576);
  }
  WVM(8); BAR();                          // tile 0 landed; 1,2 in flight

  for (int t = 0; t < KT1; ++t) {
    const int rem = KT1 - 1 - t;
    const uint8_t* b = sm + (t & 3) * 32768;
    uint8_t* lnx = sm + ((t + 3) & 3) * 32768 + tid * 16;
    const uint8_t* aa = pA + (size_t)(t + 3) * 16384;
    const uint8_t* bb = pB + (size_t)(t + 3) * 16384;
    i32x4 bv[4], avp[2];
    // ---------- phase 1: bv + av01, stage B-gate ----------
#pragma unroll
    for (int n = 0; n < 4; ++n)
      bv[n] = *reinterpret_cast<const i32x4*>(
          b + 16384 + (brow + n * 16) * 64 + slotC);
    RDA(avp[0], 0); RDA(avp[1], 1);
    if (rem >= 3) GLD16(bb, lnx + 16384);
    BAR(); LGKM0();
    MM8(0);
    // ---------- phase 2: av23, stage B-up ----------
    RDA(avp[0], 2); RDA(avp[1], 3);
    if (rem >= 3) GLD16(bb + 8192, lnx + 24576);
    BAR(); LGKM0();
    MM8(2);
    // ---------- phase 3: av45, stage A-lo ----------
    RDA(avp[0], 4); RDA(avp[1], 5);
    if (rem >= 3) GLD16(aa, lnx);
    BAR(); LGKM0();
    MM8(4);
    // ---------- phase 4: av67, stage A-hi + vmcnt ----------
    RDA(avp[0], 6); RDA(avp[1], 7);
    if (rem >= 3) {
      GLD16(aa + 8192, lnx + 8192);
      WVM(8);                      // tile t+1 landed; t+2,t+3 in flight
    } else if (rem == 2) { WVM(4); }
    else if (rem == 1)   { WVM(0); }
    BAR(); LGKM0();
    MM8(6);
  }
#undef RDA
#undef MM8

  __syncthreads();                        // K-loop LDS reads all retired
  // ---- fused epilogue: silu(gate)*up + rowmax ----
  float* gs = (float*)sm;                 // [256][128] f32 = 128KB
  const int rq = (lane >> 4) << 2;
  if (wgn < 2) {
#pragma unroll
    for (int m = 0; m < 8; ++m) {
#pragma unroll
      for (int n = 0; n < 4; ++n) {
        const int coll = (wgn << 6) + n * 16 + r15;        // 0..127 gate col
        const float wsc = wgs[ntB * 128 + coll];
#pragma unroll
        for (int r = 0; r < 4; ++r) {
          const int rowl = (wgm << 7) + m * 16 + rq + r;   // 0..255
          const float g = (float)acc[m][n][r] * xs[mt * 256 + rowl] * wsc;
          gs[rowl * 128 + (coll ^ (((rowl >> 2) & 1) << 4))] = g;
        }
      }
    }
  }
  __syncthreads();
  if (wgn >= 2) {
#pragma unroll
    for (int m = 0; m < 8; ++m) {
      float am[4] = {0.f, 0.f, 0.f, 0.f};
#pragma unroll
      for (int n = 0; n < 4; ++n) {
        const int cu = ((wgn - 2) << 6) + n * 16 + r15;    // 0..127 up col
        const float wsc = wgs[INTER + ntB * 128 + cu];
#pragma unroll
        for (int r = 0; r < 4; ++r) {
          const int rowl = (wgm << 7) + m * 16 + rq + r;
          const int grow = mt * 256 + rowl;
          const float uv = (float)acc[m][n][r] * xs[grow] * wsc;
          const float g = gs[rowl * 128 + (cu ^ (((rowl >> 2) & 1) << 4))];
          const float a = g / (1.f + __expf(-g)) * uv;
          act[(size_t)grow * INTER + ntB * 128 + cu] = f2bf(a);
          am[r] = fmaxf(am[r], __builtin_fabsf(a));
        }
      }
#pragma unroll
      for (int r = 0; r < 4; ++r) {
#pragma unroll
        for (int off = 1; off < 16; off <<= 1)
          am[r] = fmaxf(am[r], __shfl_xor(am[r], off, 64));
      }
      if (r15 == 0) {
#pragma unroll
        for (int r = 0; r < 4; ++r)
          atomicMax((int*)&mx[mt * 256 + (wgm << 7) + m * 16 + rq + r],
                    __float_as_int(am[r]));
      }
    }
  }
}

// ---------------------------------------------------------------------------
// quant: q2 = clip(rint(act * 127/mx)) -> int8 panel [16][172][128][64]
// with the pack permutation.
// ---------------------------------------------------------------------------
__global__ __launch_bounds__(256) void quant_k(
    const unsigned short* __restrict__ act, const float* __restrict__ mx,
    uint8_t* __restrict__ q2p)
{
  const int u = blockIdx.x * 256 + threadIdx.x;
  const int q = u & 3;
  const int rl = (u >> 2) & 127;
  const int s = u >> 9;
  const int mt = s / KT2;
  const int t = s - mt * KT2;
  const int row = mt * 128 + rl;
  const int col = t * 64 + ((q ^ (rl & 3)) << 4);
  const unsigned short* ap = act + (size_t)row * INTER + col;
  const float inv = 127.0f / fmaxf(mx[row], 1e-30f);
  u16x8 a0 = *reinterpret_cast<const u16x8*>(ap);
  u16x8 a1 = *reinterpret_cast<const u16x8*>(ap + 8);
  i32x4 o;
#pragma unroll
  for (int qq = 0; qq < 4; ++qq) {
    uint32_t d = 0;
#pragma unroll
    for (int b = 0; b < 4; ++b) {
      const int j = qq * 4 + b;
      float af = bf2f((j < 8) ? a0[j] : a1[j - 8]);
      float rr = rintf(af * inv);
      rr = fminf(fmaxf(rr, -127.f), 127.f);
      d |= ((uint32_t)((int)rr & 255)) << (8 * b);
    }
    o[qq] = (int)d;
  }
  *reinterpret_cast<i32x4*>(q2p + (size_t)u * 16) = o;
}

// ---------------------------------------------------------------------------
// GEMM2 (r14-measured form, untouched): 128x256 tile, 8 waves, BK=64B,
// 4-slot 24KB ring, distance-3, counted vmcnt 6/3/0, 2-phase K-step.
// ---------------------------------------------------------------------------
__global__ __launch_bounds__(512, 2) void gemm2_k(
    const uint8_t* __restrict__ q2p, const uint8_t* __restrict__ wdp,
    const float* __restrict__ mx, const float* __restrict__ wds,
    float* __restrict__ out)
{
  __shared__ uint8_t sm[98304];
  const int tid = threadIdx.x;
  const int lane = tid & 63, wid = tid >> 6;
  const int wgm = wid >> 2, wgn = wid & 3;
  const int r15 = lane & 15;
  const int slotC = (((lane >> 4) ^ (r15 & 3)) << 4);

  const int bid = blockIdx.x;
  const int v = (bid & 7) * 32 + (bid >> 3);   // XCD-chunked, bijective
  const int nt = v >> 4, mt = v & 15;

  const uint8_t* pA = q2p + (size_t)mt * (KT2 * 8192)  + tid * 16;
  const uint8_t* pB = wdp + (size_t)nt * (KT2 * 16384) + tid * 16;

  const int arow = (wgm << 6) + r15;
  const int brow = (wgn << 6) + r15;
  i32x4 acc[4][4] = {};

#define STG2(t, s) do {                                        \
    uint8_t* l = sm + (s) * 24576 + tid * 16;                  \
    GLD16(pA + (size_t)(t) * 8192, l);                         \
    const uint8_t* bb = pB + (size_t)(t) * 16384;              \
    GLD16(bb, l + 8192);                                       \
    GLD16(bb + 8192, l + 16384);                               \
  } while (0)

  STG2(0, 0); STG2(1, 1); STG2(2, 2);    // 9 loads in flight
  WVM(6); BAR();

  for (int t = 0; t < KT2; ++t) {
    const int rem = KT2 - 1 - t;
    const uint8_t* b = sm + (t & 3) * 24576;
    uint8_t* lnx = sm + ((t + 3) & 3) * 24576 + tid * 16;
    // ---------- phase A ----------
    i32x4 bv[4], av[2];
#pragma unroll
    for (int n = 0; n < 4; ++n)
      bv[n] = *reinterpret_cast<const i32x4*>(
          b + 8192 + (brow + n * 16) * 64 + slotC);
#pragma unroll
    for (int m = 0; m < 2; ++m)
      av[m] = *reinterpret_cast<const i32x4*>(b + (arow + m * 16) * 64 + slotC);
    if (rem >= 3) {
      const uint8_t* bb = pB + (size_t)(t + 3) * 16384;
      GLD16(bb, lnx + 8192);
      GLD16(bb + 8192, lnx + 16384);
    }
    BAR();
    LGKM0();
    __builtin_amdgcn_s_setprio(1);
#pragma unroll
    for (int m = 0; m < 2; ++m)
#pragma unroll
      for (int n = 0; n < 4; ++n)
        acc[m][n] = __builtin_amdgcn_mfma_i32_16x16x64_i8(
            av[m], bv[n], acc[m][n], 0, 0, 0);
    __builtin_amdgcn_s_setprio(0);
    // ---------- phase B ----------
#pragma unroll
    for (int m = 0; m < 2; ++m)
      av[m] = *reinterpret_cast<const i32x4*>(
          b + (arow + (m + 2) * 16) * 64 + slotC);
    if (rem >= 3) {
      GLD16(pA + (size_t)(t + 3) * 8192, lnx);
      WVM(6);
    } else if (rem == 2) { WVM(3); }
    else if (rem == 1)   { WVM(0); }
    BAR();
    LGKM0();
    __builtin_amdgcn_s_setprio(1);
#pragma unroll
    for (int m = 0; m < 2; ++m)
#pragma unroll
      for (int n = 0; n < 4; ++n)
        acc[m + 2][n] = __builtin_amdgcn_mfma_i32_16x16x64_i8(
            av[m], bv[n], acc[m + 2][n], 0, 0, 0);
    __builtin_amdgcn_s_setprio(0);
  }
#undef STG2

  const int rq = (lane >> 4) << 2;
#pragma unroll
  for (int m = 0; m < 4; ++m) {
#pragma unroll
    for (int r = 0; r < 4; ++r) {
      const int rowl = (wgm << 6) + m * 16 + rq + r;
      const int grow = mt * 128 + rowl;
      const float s2 = mx[grow] * (1.0f / 127.0f);
      float* op = out + (size_t)grow * HID + nt * 256 + (wgn << 6) + r15;
      const float* wp = wds + nt * 256 + (wgn << 6) + r15;
#pragma unroll
      for (int n = 0; n < 4; ++n)
        op[n * 16] = (float)acc[m][n][r] * s2 * wp[n * 16];
    }
  }
}

// ---------------------------------------------------------------------------
extern "C" void kernel_launch(void* const* d_in, const int* in_sizes, int n_in,
                              void* d_out, int out_size, void* d_ws, size_t ws_size,
                              hipStream_t stream)
{
  const int*   x_q = (const int*)d_in[0];
  const float* xs  = (const float*)d_in[1];
  const int*   wg  = (const int*)d_in[2];
  const float* wgs = (const float*)d_in[3];
  const int*   wd  = (const int*)d_in[4];
  const float* wds = (const float*)d_in[5];
  float* out = (float*)d_out;

  uint8_t* ws = (uint8_t*)d_ws;
  uint8_t* x8p = ws;                                         //   8,388,608
  uint8_t* wgp = x8p + 8388608;                              //  90,177,536
  uint8_t* wdp = wgp + 90177536;                             //  45,088,768
  unsigned short* act = (unsigned short*)(wdp + 45088768);   //  45,088,768
  float* mx = (float*)((uint8_t*)act + 45088768);            //       8,192
  uint8_t* q2p = (uint8_t*)mx + 8192;                        //  22,544,384
  // total ~211.3 MB

  zero_mx<<<2, 1024, 0, stream>>>(mx);
  pack_panel3<<<2048, 256, 0, stream>>>(x_q, x8p, 8, KT1, HID);    // A: 256-row panels
  pack_gateup<<<22016, 256, 0, stream>>>(wg, wgp);                 // B1: paired panels
  pack_panel3<<<11008, 256, 0, stream>>>(wd, wdp, 8, KT2, INTER);  // B2 panels

  gemm1_k<<<688, 512, 0, stream>>>(x8p, wgp, xs, wgs, act, mx);
  quant_k<<<5504, 256, 0, stream>>>(act, mx, q2p);
  gemm2_k<<<256, 512, 0, stream>>>(q2p, wdp, mx, wds, out);
}

// Round 18
// 436.300 us; speedup vs baseline: 1.0443x; 1.0443x over previous
//
#include <hip/hip_runtime.h>
#include <stdint.h>

typedef int i32x4 __attribute__((ext_vector_type(4)));
typedef unsigned short u16x8 __attribute__((ext_vector_type(8)));

#define N_TOK 2048
#define HID   4096
#define INTER 11008
#define TWOI  22016
#define KT1   64     // HID/64   k-steps for gemm1
#define KT2   172    // INTER/64 k-steps for gemm2

#define GLD16(gp, lp) __builtin_amdgcn_global_load_lds( \
    (const __attribute__((address_space(1))) void*)(gp), \
    (__attribute__((address_space(3))) void*)(lp), 16, 0, 0)
#define BAR() __builtin_amdgcn_s_barrier()
#define WVM(n) asm volatile("s_waitcnt vmcnt(" #n ")" ::: "memory")
// rule #18: lgkmcnt asm must be followed by sched_barrier(0).
#define LGKM0() do { asm volatile("s_waitcnt lgkmcnt(0)" ::: "memory"); \
                     __builtin_amdgcn_sched_barrier(0); } while (0)

__device__ __forceinline__ unsigned short f2bf(float f) {
  uint32_t u = __float_as_uint(f);
  uint32_t r = (u + 0x7fffu + ((u >> 16) & 1u)) >> 16;
  return (unsigned short)r;
}

__device__ __forceinline__ float bf2f(unsigned short b) {
  return __uint_as_float(((uint32_t)b) << 16);
}

// ---------------------------------------------------------------------------
// pack_frag: int32 [R][K] -> int8 FRAGMENT-MAJOR panels:
//   [p][kt][frag f][lane l][16B],  frag = PR/16 per step,
//   byte(f,l) holds src[p*PR + f*16 + (l&15)][kt*64 + (l>>4)*16 .. +15].
// A wave's ds_read_b128 of one fragment (lane l at f*1024 + l*16) is then
// 1024 CONTIGUOUS bytes -> zero bank conflicts by construction. Staging via
// global_load_lds stays a linear identity copy.
// ---------------------------------------------------------------------------
__global__ __launch_bounds__(256) void pack_frag(
    const int* __restrict__ src, uint8_t* __restrict__ dst,
    int lgPR, int KT, int K)
{
  const int u = blockIdx.x * 256 + threadIdx.x;
  const int l = u & 63;
  const int rest = u >> 6;
  const int f = rest & ((1 << (lgPR - 4)) - 1);
  const int s = rest >> (lgPR - 4);
  const int p = s / KT;
  const int kt = s - p * KT;
  const int row = (p << lgPR) + f * 16 + (l & 15);
  const int col = kt * 64 + ((l >> 4) << 4);
  const int* sp = src + (size_t)row * K + col;
  i32x4 o;
#pragma unroll
  for (int qq = 0; qq < 4; ++qq) {
    i32x4 w = *reinterpret_cast<const i32x4*>(sp + qq * 4);
    o[qq] = (w[0] & 255) | ((w[1] & 255) << 8) | ((w[2] & 255) << 16)
          | ((w[3] & 255) << 24);
  }
  *reinterpret_cast<i32x4*>(dst + (size_t)u * 16) = o;
}

// ---------------------------------------------------------------------------
// GEMM1 (r14-frozen schedule): 256x256 tile, 8 waves (2Mx4N, wave 128x64),
// BK=64B, 4-slot 32KB ring (128KB LDS), distance-3, vmcnt 8/4/0, 2-phase
// K-step. Fragment-major LDS: A-frag m at (wgm*8+m)*1024 + lane*16,
// B-frag n at 16384 + (wgn*4+n)*1024 + lane*16 — contiguous reads.
// Epilogue: plain dequant -> bf16 gu store.
// ---------------------------------------------------------------------------
__global__ __launch_bounds__(512, 2) void gemm1_k(
    const uint8_t* __restrict__ x8p, const uint8_t* __restrict__ wgp,
    const float* __restrict__ xs, const float* __restrict__ wgs,
    unsigned short* __restrict__ gu)
{
  __shared__ uint8_t sm[131072];         // 4 slots x (A 16KB + B 16KB)
  const int tid = threadIdx.x;
  const int lane = tid & 63, wid = tid >> 6;
  const int wgm = wid >> 2, wgn = wid & 3;
  const int r15 = lane & 15;
  const int l16 = lane * 16;
  const int aBase = (wgm << 13) + l16;            // wgm*8192
  const int bBase = 16384 + (wgn << 12) + l16;    // 16384 + wgn*4096

  const int bid = blockIdx.x;
  const int v = (bid & 7) * 86 + (bid >> 3);   // 688 = 8*86, bijective
  const int mt = v & 7;                        // 8 M-tiles of 256
  const int ntB = v >> 3;                      // 86 col-tiles of 256

  const uint8_t* pA = x8p + (size_t)mt  * (KT1 * 16384) + tid * 16;
  const uint8_t* pB = wgp + (size_t)ntB * (KT1 * 16384) + tid * 16;

  i32x4 acc[8][4] = {};

#define STG1(t, s) do {                                        \
    uint8_t* l = sm + (s) * 32768 + tid * 16;                  \
    const uint8_t* aa = pA + (size_t)(t) * 16384;              \
    GLD16(aa, l);                                              \
    GLD16(aa + 8192, l + 8192);                                \
    const uint8_t* bb = pB + (size_t)(t) * 16384;              \
    GLD16(bb, l + 16384);                                      \
    GLD16(bb + 8192, l + 24576);                               \
  } while (0)

  STG1(0, 0); STG1(1, 1); STG1(2, 2);    // 12 loads in flight
  WVM(8); BAR();                          // tile 0 landed; 1,2 in flight

  for (int t = 0; t < KT1; ++t) {
    const int rem = KT1 - 1 - t;
    const uint8_t* b = sm + (t & 3) * 32768;
    uint8_t* lnx = sm + ((t + 3) & 3) * 32768 + tid * 16;
    // ---------- phase A: B-frags + A-low, stage next B ----------
    i32x4 bv[4], av[4];
#pragma unroll
    for (int n = 0; n < 4; ++n)
      bv[n] = *reinterpret_cast<const i32x4*>(b + bBase + n * 1024);
#pragma unroll
    for (int m = 0; m < 4; ++m)
      av[m] = *reinterpret_cast<const i32x4*>(b + aBase + m * 1024);
    if (rem >= 3) {
      const uint8_t* bb = pB + (size_t)(t + 3) * 16384;
      GLD16(bb, lnx + 16384);
      GLD16(bb + 8192, lnx + 24576);
    }
    BAR();
    LGKM0();
    __builtin_amdgcn_s_setprio(1);
#pragma unroll
    for (int m = 0; m < 4; ++m)
#pragma unroll
      for (int n = 0; n < 4; ++n)
        acc[m][n] = __builtin_amdgcn_mfma_i32_16x16x64_i8(
            av[m], bv[n], acc[m][n], 0, 0, 0);
    __builtin_amdgcn_s_setprio(0);
    // ---------- phase B: A-high, stage next A ----------
#pragma unroll
    for (int m = 0; m < 4; ++m)
      av[m] = *reinterpret_cast<const i32x4*>(b + aBase + (m + 4) * 1024);
    if (rem >= 3) {
      const uint8_t* aa = pA + (size_t)(t + 3) * 16384;
      GLD16(aa, lnx);
      GLD16(aa + 8192, lnx + 8192);
      WVM(8);                      // tile t+1 landed; t+2,t+3 in flight
    } else if (rem == 2) { WVM(4); }
    else if (rem == 1)   { WVM(0); }
    BAR();
    LGKM0();
    __builtin_amdgcn_s_setprio(1);
#pragma unroll
    for (int m = 0; m < 4; ++m)
#pragma unroll
      for (int n = 0; n < 4; ++n)
        acc[m + 4][n] = __builtin_amdgcn_mfma_i32_16x16x64_i8(
            av[m], bv[n], acc[m + 4][n], 0, 0, 0);
    __builtin_amdgcn_s_setprio(0);
  }
#undef STG1

  const int rq = (lane >> 4) << 2;
#pragma unroll
  for (int m = 0; m < 8; ++m) {
#pragma unroll
    for (int r = 0; r < 4; ++r) {
      const int rowl = (wgm << 7) + m * 16 + rq + r;
      const int grow = mt * 256 + rowl;
      const float xr = xs[grow];
      const int colb = ntB * 256 + (wgn << 6) + r15;
      unsigned short* op = gu + (size_t)grow * TWOI + colb;
      const float* wp = wgs + colb;
#pragma unroll
      for (int n = 0; n < 4; ++n)
        op[n * 16] = f2bf((float)acc[m][n][r] * xr * wp[n * 16]);
    }
  }
}

// ---------------------------------------------------------------------------
// rowmax: one block per token row; mx[row] = max|silu(g)*u|.
// ---------------------------------------------------------------------------
__global__ __launch_bounds__(256) void rowmax_k(
    const unsigned short* __restrict__ gu, float* __restrict__ mx)
{
  const int row = blockIdx.x;
  const unsigned short* gp = gu + (size_t)row * TWOI;
  float m = 0.f;
  for (int i = threadIdx.x; i < INTER / 8; i += 256) {
    u16x8 gv = *reinterpret_cast<const u16x8*>(gp + i * 8);
    u16x8 uv = *reinterpret_cast<const u16x8*>(gp + INTER + i * 8);
#pragma unroll
    for (int j = 0; j < 8; ++j) {
      float gf = bf2f(gv[j]);
      float uf = bf2f(uv[j]);
      float a = (gf / (1.f + __expf(-gf))) * uf;
      m = fmaxf(m, __builtin_fabsf(a));
    }
  }
#pragma unroll
  for (int o = 32; o; o >>= 1) m = fmaxf(m, __shfl_xor(m, o, 64));
  __shared__ float red[4];
  const int lane = threadIdx.x & 63, wid = threadIdx.x >> 6;
  if (lane == 0) red[wid] = m;
  __syncthreads();
  if (threadIdx.x == 0)
    mx[row] = fmaxf(fmaxf(red[0], red[1]), fmaxf(red[2], red[3]));
}

// ---------------------------------------------------------------------------
// quant: recompute act = silu(g)*u, q2 = clip(rint(act*127/mx)) -> int8
// FRAGMENT-MAJOR panel (PR=128, 8 frags/step, 16 panels x KT2 steps).
// One 16B unit per thread, coalesced writes.
// ---------------------------------------------------------------------------
__global__ __launch_bounds__(256) void quant_k(
    const unsigned short* __restrict__ gu, const float* __restrict__ mx,
    uint8_t* __restrict__ q2p)
{
  const int u = blockIdx.x * 256 + threadIdx.x;
  const int l = u & 63;
  const int rest = u >> 6;
  const int f = rest & 7;                // 8 frags (PR=128)
  const int s = rest >> 3;
  const int mt = s / KT2;
  const int t = s - mt * KT2;
  const int row = mt * 128 + f * 16 + (l & 15);
  const int col = t * 64 + ((l >> 4) << 4);
  const unsigned short* gp = gu + (size_t)row * TWOI + col;
  const float inv = 127.0f / fmaxf(mx[row], 1e-30f);
  u16x8 g0 = *reinterpret_cast<const u16x8*>(gp);
  u16x8 g1 = *reinterpret_cast<const u16x8*>(gp + 8);
  u16x8 u0 = *reinterpret_cast<const u16x8*>(gp + INTER);
  u16x8 u1 = *reinterpret_cast<const u16x8*>(gp + INTER + 8);
  i32x4 o;
#pragma unroll
  for (int qq = 0; qq < 4; ++qq) {
    uint32_t d = 0;
#pragma unroll
    for (int b = 0; b < 4; ++b) {
      const int j = qq * 4 + b;
      float gf = bf2f((j < 8) ? g0[j] : g1[j - 8]);
      float uf = bf2f((j < 8) ? u0[j] : u1[j - 8]);
      float a = (gf / (1.f + __expf(-gf))) * uf;
      float rr = rintf(a * inv);
      rr = fminf(fmaxf(rr, -127.f), 127.f);
      d |= ((uint32_t)((int)rr & 255)) << (8 * b);
    }
    o[qq] = (int)d;
  }
  *reinterpret_cast<i32x4*>(q2p + (size_t)u * 16) = o;
}

// ---------------------------------------------------------------------------
// GEMM2 (r14-frozen schedule): 128x256 tile, 8 waves, BK=64B, 4-slot 24KB
// ring, distance-3, vmcnt 6/3/0, 2-phase K-step. Fragment-major LDS:
// A-frag m at (wgm*4+m)*1024, B-frag n at 8192 + (wgn*4+n)*1024.
// ---------------------------------------------------------------------------
__global__ __launch_bounds__(512, 2) void gemm2_k(
    const uint8_t* __restrict__ q2p, const uint8_t* __restrict__ wdp,
    const float* __restrict__ mx, const float* __restrict__ wds,
    float* __restrict__ out)
{
  __shared__ uint8_t sm[98304];
  const int tid = threadIdx.x;
  const int lane = tid & 63, wid = tid >> 6;
  const int wgm = wid >> 2, wgn = wid & 3;
  const int r15 = lane & 15;
  const int l16 = lane * 16;
  const int aBase = (wgm << 12) + l16;            // wgm*4096
  const int bBase = 8192 + (wgn << 12) + l16;     // 8192 + wgn*4096

  const int bid = blockIdx.x;
  const int v = (bid & 7) * 32 + (bid >> 3);   // XCD-chunked, bijective
  const int nt = v >> 4, mt = v & 15;

  const uint8_t* pA = q2p + (size_t)mt * (KT2 * 8192)  + tid * 16;
  const uint8_t* pB = wdp + (size_t)nt * (KT2 * 16384) + tid * 16;

  i32x4 acc[4][4] = {};

#define STG2(t, s) do {                                        \
    uint8_t* l = sm + (s) * 24576 + tid * 16;                  \
    GLD16(pA + (size_t)(t) * 8192, l);                         \
    const uint8_t* bb = pB + (size_t)(t) * 16384;              \
    GLD16(bb, l + 8192);                                       \
    GLD16(bb + 8192, l + 16384);                               \
  } while (0)

  STG2(0, 0); STG2(1, 1); STG2(2, 2);    // 9 loads in flight
  WVM(6); BAR();

  for (int t = 0; t < KT2; ++t) {
    const int rem = KT2 - 1 - t;
    const uint8_t* b = sm + (t & 3) * 24576;
    uint8_t* lnx = sm + ((t + 3) & 3) * 24576 + tid * 16;
    // ---------- phase A ----------
    i32x4 bv[4], av[2];
#pragma unroll
    for (int n = 0; n < 4; ++n)
      bv[n] = *reinterpret_cast<const i32x4*>(b + bBase + n * 1024);
#pragma unroll
    for (int m = 0; m < 2; ++m)
      av[m] = *reinterpret_cast<const i32x4*>(b + aBase + m * 1024);
    if (rem >= 3) {
      const uint8_t* bb = pB + (size_t)(t + 3) * 16384;
      GLD16(bb, lnx + 8192);
      GLD16(bb + 8192, lnx + 16384);
    }
    BAR();
    LGKM0();
    __builtin_amdgcn_s_setprio(1);
#pragma unroll
    for (int m = 0; m < 2; ++m)
#pragma unroll
      for (int n = 0; n < 4; ++n)
        acc[m][n] = __builtin_amdgcn_mfma_i32_16x16x64_i8(
            av[m], bv[n], acc[m][n], 0, 0, 0);
    __builtin_amdgcn_s_setprio(0);
    // ---------- phase B ----------
#pragma unroll
    for (int m = 0; m < 2; ++m)
      av[m] = *reinterpret_cast<const i32x4*>(b + aBase + (m + 2) * 1024);
    if (rem >= 3) {
      GLD16(pA + (size_t)(t + 3) * 8192, lnx);
      WVM(6);
    } else if (rem == 2) { WVM(3); }
    else if (rem == 1)   { WVM(0); }
    BAR();
    LGKM0();
    __builtin_amdgcn_s_setprio(1);
#pragma unroll
    for (int m = 0; m < 2; ++m)
#pragma unroll
      for (int n = 0; n < 4; ++n)
        acc[m + 2][n] = __builtin_amdgcn_mfma_i32_16x16x64_i8(
            av[m], bv[n], acc[m + 2][n], 0, 0, 0);
    __builtin_amdgcn_s_setprio(0);
  }
#undef STG2

  const int rq = (lane >> 4) << 2;
#pragma unroll
  for (int m = 0; m < 4; ++m) {
#pragma unroll
    for (int r = 0; r < 4; ++r) {
      const int rowl = (wgm << 6) + m * 16 + rq + r;
      const int grow = mt * 128 + rowl;
      const float s2 = mx[grow] * (1.0f / 127.0f);
      float* op = out + (size_t)grow * HID + nt * 256 + (wgn << 6) + r15;
      const float* wp = wds + nt * 256 + (wgn << 6) + r15;
#pragma unroll
      for (int n = 0; n < 4; ++n)
        op[n * 16] = (float)acc[m][n][r] * s2 * wp[n * 16];
    }
  }
}

// ---------------------------------------------------------------------------
extern "C" void kernel_launch(void* const* d_in, const int* in_sizes, int n_in,
                              void* d_out, int out_size, void* d_ws, size_t ws_size,
                              hipStream_t stream)
{
  const int*   x_q = (const int*)d_in[0];
  const float* xs  = (const float*)d_in[1];
  const int*   wg  = (const int*)d_in[2];
  const float* wgs = (const float*)d_in[3];
  const int*   wd  = (const int*)d_in[4];
  const float* wds = (const float*)d_in[5];
  float* out = (float*)d_out;

  uint8_t* ws = (uint8_t*)d_ws;
  uint8_t* x8p = ws;                                         //   8,388,608
  uint8_t* wgp = x8p + 8388608;                              //  90,177,536
  uint8_t* wdp = wgp + 90177536;                             //  45,088,768
  unsigned short* gu = (unsigned short*)(wdp + 45088768);    //  90,177,536
  float* mx = (float*)((uint8_t*)gu + 90177536);             //       8,192
  uint8_t* q2p = (uint8_t*)mx + 8192;                        //  22,544,384
  // total ~256.4 MB

  pack_frag<<<2048, 256, 0, stream>>>(x_q, x8p, 8, KT1, HID);    // A: 256-row panels
  pack_frag<<<22016, 256, 0, stream>>>(wg, wgp, 8, KT1, HID);    // B1 panels
  pack_frag<<<11008, 256, 0, stream>>>(wd, wdp, 8, KT2, INTER);  // B2 panels

  gemm1_k<<<688, 512, 0, stream>>>(x8p, wgp, xs, wgs, gu);
  rowmax_k<<<N_TOK, 256, 0, stream>>>(gu, mx);
  quant_k<<<5504, 256, 0, stream>>>(gu, mx, q2p);
  gemm2_k<<<256, 512, 0, stream>>>(q2p, wdp, mx, wds, out);
}

// Round 19
// 433.403 us; speedup vs baseline: 1.0512x; 1.0067x over previous
//
#include <hip/hip_runtime.h>
#include <stdint.h>

typedef int i32x4 __attribute__((ext_vector_type(4)));
typedef unsigned short u16x8 __attribute__((ext_vector_type(8)));

#define N_TOK 2048
#define HID   4096
#define INTER 11008
#define TWOI  22016
#define KT1   64     // HID/64   k-steps for gemm1
#define KT2   172    // INTER/64 k-steps for gemm2

#define GLD16(gp, lp) __builtin_amdgcn_global_load_lds( \
    (const __attribute__((address_space(1))) void*)(gp), \
    (__attribute__((address_space(3))) void*)(lp), 16, 0, 0)
#define BAR() __builtin_amdgcn_s_barrier()
#define WVM(n) asm volatile("s_waitcnt vmcnt(" #n ")" ::: "memory")
// rule #18: lgkmcnt asm must be followed by sched_barrier(0).
#define LGKM0() do { asm volatile("s_waitcnt lgkmcnt(0)" ::: "memory"); \
                     __builtin_amdgcn_sched_barrier(0); } while (0)

__device__ __forceinline__ unsigned short f2bf(float f) {
  uint32_t u = __float_as_uint(f);
  uint32_t r = (u + 0x7fffu + ((u >> 16) & 1u)) >> 16;
  return (unsigned short)r;
}

__device__ __forceinline__ float bf2f(unsigned short b) {
  return __uint_as_float(((uint32_t)b) << 16);
}

// ---------------------------------------------------------------------------
// pack_frag: int32 [R][K] -> int8 FRAGMENT-MAJOR panels
//   [p][kt][frag f][lane l][16B]: byte(f,l) = src[p*PR + f*16 + (l&15)]
//   [kt*64 + (l>>4)*16 .. +15]. Fragment ds_read_b128 = 1024 contiguous
//   bytes -> zero bank conflicts; global_load_lds staging stays linear.
// ---------------------------------------------------------------------------
__global__ __launch_bounds__(256) void pack_frag(
    const int* __restrict__ src, uint8_t* __restrict__ dst,
    int lgPR, int KT, int K)
{
  const int u = blockIdx.x * 256 + threadIdx.x;
  const int l = u & 63;
  const int rest = u >> 6;
  const int f = rest & ((1 << (lgPR - 4)) - 1);
  const int s = rest >> (lgPR - 4);
  const int p = s / KT;
  const int kt = s - p * KT;
  const int row = (p << lgPR) + f * 16 + (l & 15);
  const int col = kt * 64 + ((l >> 4) << 4);
  const int* sp = src + (size_t)row * K + col;
  i32x4 o;
#pragma unroll
  for (int qq = 0; qq < 4; ++qq) {
    i32x4 w = *reinterpret_cast<const i32x4*>(sp + qq * 4);
    o[qq] = (w[0] & 255) | ((w[1] & 255) << 8) | ((w[2] & 255) << 16)
          | ((w[3] & 255) << 24);
  }
  *reinterpret_cast<i32x4*>(dst + (size_t)u * 16) = o;
}

// ---------------------------------------------------------------------------
// pack_gufrag: w_gateup int32 [2I][H] -> frag-major panels [86][KT1][16f][64l]
// with gate/up INTERLEAVED at fragment granularity:
//   frag 2j   = gate rows  ntB*128 + 16j .. +15
//   frag 2j+1 = up rows    INTER + ntB*128 + 16j .. +15
// -> in gemm1, acc[m][2p] (gate) and acc[m][2p+1] (up) hold the SAME
// (row, act-col) pair in registers: silu fusion needs no cross-wave exchange.
// ---------------------------------------------------------------------------
__global__ __launch_bounds__(256) void pack_gufrag(
    const int* __restrict__ src, uint8_t* __restrict__ dst)
{
  const int u = blockIdx.x * 256 + threadIdx.x;
  const int l = u & 63;
  const int rest = u >> 6;
  const int fi = rest & 15;
  const int s = rest >> 4;
  const int p = s / KT1;
  const int kt = s - p * KT1;
  const int base = p * 128 + ((fi >> 1) << 4) + (l & 15);
  const int srow = (fi & 1) ? (INTER + base) : base;
  const int col = kt * 64 + ((l >> 4) << 4);
  const int* sp = src + (size_t)srow * HID + col;
  i32x4 o;
#pragma unroll
  for (int qq = 0; qq < 4; ++qq) {
    i32x4 w = *reinterpret_cast<const i32x4*>(sp + qq * 4);
    o[qq] = (w[0] & 255) | ((w[1] & 255) << 8) | ((w[2] & 255) << 16)
          | ((w[3] & 255) << 24);
  }
  *reinterpret_cast<i32x4*>(dst + (size_t)u * 16) = o;
}

__global__ __launch_bounds__(1024) void zero_mx(float* __restrict__ mx) {
  const int i = blockIdx.x * 1024 + threadIdx.x;
  if (i < N_TOK) mx[i] = 0.0f;
}

// ---------------------------------------------------------------------------
// GEMM1 (r18-frozen K-loop): 256x256 tile, 8 waves (2Mx4N, wave 128x64),
// BK=64B, 4-slot 32KB ring (128KB LDS), distance-3, vmcnt 8/4/0, 2-phase
// K-step, fragment-major LDS (contiguous reads). B covers 128 gate + 128 up
// matched rows (interleaved frags). Epilogue: in-register silu(g)*u ->
// act bf16 [N][I] + per-row atomicMax -> mx. No LDS, no rowmax kernel.
// ---------------------------------------------------------------------------
__global__ __launch_bounds__(512, 2) void gemm1_k(
    const uint8_t* __restrict__ x8p, const uint8_t* __restrict__ wgp,
    const float* __restrict__ xs, const float* __restrict__ wgs,
    unsigned short* __restrict__ act, float* __restrict__ mx)
{
  __shared__ uint8_t sm[131072];         // 4 slots x (A 16KB + B 16KB)
  const int tid = threadIdx.x;
  const int lane = tid & 63, wid = tid >> 6;
  const int wgm = wid >> 2, wgn = wid & 3;
  const int r15 = lane & 15;
  const int l16 = lane * 16;
  const int aBase = (wgm << 13) + l16;            // wgm*8192
  const int bBase = 16384 + (wgn << 12) + l16;    // 16384 + wgn*4096

  const int bid = blockIdx.x;
  const int v = (bid & 7) * 86 + (bid >> 3);   // 688 = 8*86, bijective
  const int mt = v & 7;                        // 8 M-tiles of 256
  const int ntB = v >> 3;                      // 86 act-col tiles of 128

  const uint8_t* pA = x8p + (size_t)mt  * (KT1 * 16384) + tid * 16;
  const uint8_t* pB = wgp + (size_t)ntB * (KT1 * 16384) + tid * 16;

  i32x4 acc[8][4] = {};

#define STG1(t, s) do {                                        \
    uint8_t* l = sm + (s) * 32768 + tid * 16;                  \
    const uint8_t* aa = pA + (size_t)(t) * 16384;              \
    GLD16(aa, l);                                              \
    GLD16(aa + 8192, l + 8192);                                \
    const uint8_t* bb = pB + (size_t)(t) * 16384;              \
    GLD16(bb, l + 16384);                                      \
    GLD16(bb + 8192, l + 24576);                               \
  } while (0)

  STG1(0, 0); STG1(1, 1); STG1(2, 2);    // 12 loads in flight
  WVM(8); BAR();                          // tile 0 landed; 1,2 in flight

  for (int t = 0; t < KT1; ++t) {
    const int rem = KT1 - 1 - t;
    const uint8_t* b = sm + (t & 3) * 32768;
    uint8_t* lnx = sm + ((t + 3) & 3) * 32768 + tid * 16;
    // ---------- phase A: B-frags + A-low, stage next B ----------
    i32x4 bv[4], av[4];
#pragma unroll
    for (int n = 0; n < 4; ++n)
      bv[n] = *reinterpret_cast<const i32x4*>(b + bBase + n * 1024);
#pragma unroll
    for (int m = 0; m < 4; ++m)
      av[m] = *reinterpret_cast<const i32x4*>(b + aBase + m * 1024);
    if (rem >= 3) {
      const uint8_t* bb = pB + (size_t)(t + 3) * 16384;
      GLD16(bb, lnx + 16384);
      GLD16(bb + 8192, lnx + 24576);
    }
    BAR();
    LGKM0();
    __builtin_amdgcn_s_setprio(1);
#pragma unroll
    for (int m = 0; m < 4; ++m)
#pragma unroll
      for (int n = 0; n < 4; ++n)
        acc[m][n] = __builtin_amdgcn_mfma_i32_16x16x64_i8(
            av[m], bv[n], acc[m][n], 0, 0, 0);
    __builtin_amdgcn_s_setprio(0);
    // ---------- phase B: A-high, stage next A ----------
#pragma unroll
    for (int m = 0; m < 4; ++m)
      av[m] = *reinterpret_cast<const i32x4*>(b + aBase + (m + 4) * 1024);
    if (rem >= 3) {
      const uint8_t* aa = pA + (size_t)(t + 3) * 16384;
      GLD16(aa, lnx);
      GLD16(aa + 8192, lnx + 8192);
      WVM(8);                      // tile t+1 landed; t+2,t+3 in flight
    } else if (rem == 2) { WVM(4); }
    else if (rem == 1)   { WVM(0); }
    BAR();
    LGKM0();
    __builtin_amdgcn_s_setprio(1);
#pragma unroll
    for (int m = 0; m < 4; ++m)
#pragma unroll
      for (int n = 0; n < 4; ++n)
        acc[m + 4][n] = __builtin_amdgcn_mfma_i32_16x16x64_i8(
            av[m], bv[n], acc[m + 4][n], 0, 0, 0);
    __builtin_amdgcn_s_setprio(0);
  }
#undef STG1

  // ---- fused epilogue: silu(gate)*up in registers + rowmax ----
  // acc[m][2p] = gate(row, col p), acc[m][2p+1] = up(row, col p):
  // col = ntB*128 + wgn*32 + p*16 + r15.
  const int rq = (lane >> 4) << 2;
#pragma unroll
  for (int m = 0; m < 8; ++m) {
    float am[4] = {0.f, 0.f, 0.f, 0.f};
#pragma unroll
    for (int p = 0; p < 2; ++p) {
      const int colb = ntB * 128 + (wgn << 5) + (p << 4) + r15;
      const float gsc = wgs[colb];
      const float usc = wgs[INTER + colb];
#pragma unroll
      for (int r = 0; r < 4; ++r) {
        const int rowl = (wgm << 7) + m * 16 + rq + r;
        const int grow = mt * 256 + rowl;
        const float xr = xs[grow];
        const float g  = (float)acc[m][2 * p][r] * xr * gsc;
        const float uv = (float)acc[m][2 * p + 1][r] * xr * usc;
        const float a  = g / (1.f + __expf(-g)) * uv;
        act[(size_t)grow * INTER + colb] = f2bf(a);
        am[r] = fmaxf(am[r], __builtin_fabsf(a));
      }
    }
#pragma unroll
    for (int r = 0; r < 4; ++r)
#pragma unroll
      for (int off = 1; off < 16; off <<= 1)
        am[r] = fmaxf(am[r], __shfl_xor(am[r], off, 64));
    if (r15 == 0) {
#pragma unroll
      for (int r = 0; r < 4; ++r)
        atomicMax((int*)&mx[mt * 256 + (wgm << 7) + m * 16 + rq + r],
                  __float_as_int(am[r]));
    }
  }
}

// ---------------------------------------------------------------------------
// quant: q2 = clip(rint(act * 127/mx)) -> int8 FRAGMENT-MAJOR panel
// (PR=128, 8 frags/step, 16 panels x KT2 steps). No silu recompute.
// ---------------------------------------------------------------------------
__global__ __launch_bounds__(256) void quant_k(
    const unsigned short* __restrict__ act, const float* __restrict__ mx,
    uint8_t* __restrict__ q2p)
{
  const int u = blockIdx.x * 256 + threadIdx.x;
  const int l = u & 63;
  const int rest = u >> 6;
  const int f = rest & 7;                // 8 frags (PR=128)
  const int s = rest >> 3;
  const int mt = s / KT2;
  const int t = s - mt * KT2;
  const int row = mt * 128 + f * 16 + (l & 15);
  const int col = t * 64 + ((l >> 4) << 4);
  const unsigned short* ap = act + (size_t)row * INTER + col;
  const float inv = 127.0f / fmaxf(mx[row], 1e-30f);
  u16x8 a0 = *reinterpret_cast<const u16x8*>(ap);
  u16x8 a1 = *reinterpret_cast<const u16x8*>(ap + 8);
  i32x4 o;
#pragma unroll
  for (int qq = 0; qq < 4; ++qq) {
    uint32_t d = 0;
#pragma unroll
    for (int b = 0; b < 4; ++b) {
      const int j = qq * 4 + b;
      float af = bf2f((j < 8) ? a0[j] : a1[j - 8]);
      float rr = rintf(af * inv);
      rr = fminf(fmaxf(rr, -127.f), 127.f);
      d |= ((uint32_t)((int)rr & 255)) << (8 * b);
    }
    o[qq] = (int)d;
  }
  *reinterpret_cast<i32x4*>(q2p + (size_t)u * 16) = o;
}

// ---------------------------------------------------------------------------
// GEMM2 (r18-frozen): 128x256 tile, 8 waves, BK=64B, 4-slot 24KB ring,
// distance-3, vmcnt 6/3/0, 2-phase K-step, fragment-major LDS.
// ---------------------------------------------------------------------------
__global__ __launch_bounds__(512, 2) void gemm2_k(
    const uint8_t* __restrict__ q2p, const uint8_t* __restrict__ wdp,
    const float* __restrict__ mx, const float* __restrict__ wds,
    float* __restrict__ out)
{
  __shared__ uint8_t sm[98304];
  const int tid = threadIdx.x;
  const int lane = tid & 63, wid = tid >> 6;
  const int wgm = wid >> 2, wgn = wid & 3;
  const int r15 = lane & 15;
  const int l16 = lane * 16;
  const int aBase = (wgm << 12) + l16;            // wgm*4096
  const int bBase = 8192 + (wgn << 12) + l16;     // 8192 + wgn*4096

  const int bid = blockIdx.x;
  const int v = (bid & 7) * 32 + (bid >> 3);   // XCD-chunked, bijective
  const int nt = v >> 4, mt = v & 15;

  const uint8_t* pA = q2p + (size_t)mt * (KT2 * 8192)  + tid * 16;
  const uint8_t* pB = wdp + (size_t)nt * (KT2 * 16384) + tid * 16;

  i32x4 acc[4][4] = {};

#define STG2(t, s) do {                                        \
    uint8_t* l = sm + (s) * 24576 + tid * 16;                  \
    GLD16(pA + (size_t)(t) * 8192, l);                         \
    const uint8_t* bb = pB + (size_t)(t) * 16384;              \
    GLD16(bb, l + 8192);                                       \
    GLD16(bb + 8192, l + 16384);                               \
  } while (0)

  STG2(0, 0); STG2(1, 1); STG2(2, 2);    // 9 loads in flight
  WVM(6); BAR();

  for (int t = 0; t < KT2; ++t) {
    const int rem = KT2 - 1 - t;
    const uint8_t* b = sm + (t & 3) * 24576;
    uint8_t* lnx = sm + ((t + 3) & 3) * 24576 + tid * 16;
    // ---------- phase A ----------
    i32x4 bv[4], av[2];
#pragma unroll
    for (int n = 0; n < 4; ++n)
      bv[n] = *reinterpret_cast<const i32x4*>(b + bBase + n * 1024);
#pragma unroll
    for (int m = 0; m < 2; ++m)
      av[m] = *reinterpret_cast<const i32x4*>(b + aBase + m * 1024);
    if (rem >= 3) {
      const uint8_t* bb = pB + (size_t)(t + 3) * 16384;
      GLD16(bb, lnx + 8192);
      GLD16(bb + 8192, lnx + 16384);
    }
    BAR();
    LGKM0();
    __builtin_amdgcn_s_setprio(1);
#pragma unroll
    for (int m = 0; m < 2; ++m)
#pragma unroll
      for (int n = 0; n < 4; ++n)
        acc[m][n] = __builtin_amdgcn_mfma_i32_16x16x64_i8(
            av[m], bv[n], acc[m][n], 0, 0, 0);
    __builtin_amdgcn_s_setprio(0);
    // ---------- phase B ----------
#pragma unroll
    for (int m = 0; m < 2; ++m)
      av[m] = *reinterpret_cast<const i32x4*>(b + aBase + (m + 2) * 1024);
    if (rem >= 3) {
      GLD16(pA + (size_t)(t + 3) * 8192, lnx);
      WVM(6);
    } else if (rem == 2) { WVM(3); }
    else if (rem == 1)   { WVM(0); }
    BAR();
    LGKM0();
    __builtin_amdgcn_s_setprio(1);
#pragma unroll
    for (int m = 0; m < 2; ++m)
#pragma unroll
      for (int n = 0; n < 4; ++n)
        acc[m + 2][n] = __builtin_amdgcn_mfma_i32_16x16x64_i8(
            av[m], bv[n], acc[m + 2][n], 0, 0, 0);
    __builtin_amdgcn_s_setprio(0);
  }
#undef STG2

  const int rq = (lane >> 4) << 2;
#pragma unroll
  for (int m = 0; m < 4; ++m) {
#pragma unroll
    for (int r = 0; r < 4; ++r) {
      const int rowl = (wgm << 6) + m * 16 + rq + r;
      const int grow = mt * 128 + rowl;
      const float s2 = mx[grow] * (1.0f / 127.0f);
      float* op = out + (size_t)grow * HID + nt * 256 + (wgn << 6) + r15;
      const float* wp = wds + nt * 256 + (wgn << 6) + r15;
#pragma unroll
      for (int n = 0; n < 4; ++n)
        op[n * 16] = (float)acc[m][n][r] * s2 * wp[n * 16];
    }
  }
}

// ---------------------------------------------------------------------------
extern "C" void kernel_launch(void* const* d_in, const int* in_sizes, int n_in,
                              void* d_out, int out_size, void* d_ws, size_t ws_size,
                              hipStream_t stream)
{
  const int*   x_q = (const int*)d_in[0];
  const float* xs  = (const float*)d_in[1];
  const int*   wg  = (const int*)d_in[2];
  const float* wgs = (const float*)d_in[3];
  const int*   wd  = (const int*)d_in[4];
  const float* wds = (const float*)d_in[5];
  float* out = (float*)d_out;

  uint8_t* ws = (uint8_t*)d_ws;
  uint8_t* x8p = ws;                                         //   8,388,608
  uint8_t* wgp = x8p + 8388608;                              //  90,177,536
  uint8_t* wdp = wgp + 90177536;                             //  45,088,768
  unsigned short* act = (unsigned short*)(wdp + 45088768);   //  45,088,768
  float* mx = (float*)((uint8_t*)act + 45088768);            //       8,192
  uint8_t* q2p = (uint8_t*)mx + 8192;                        //  22,544,384
  // total ~211.3 MB

  zero_mx<<<2, 1024, 0, stream>>>(mx);
  pack_frag<<<2048, 256, 0, stream>>>(x_q, x8p, 8, KT1, HID);    // A panels
  pack_gufrag<<<22016, 256, 0, stream>>>(wg, wgp);               // B1 interleaved
  pack_frag<<<11008, 256, 0, stream>>>(wd, wdp, 8, KT2, INTER);  // B2 panels

  gemm1_k<<<688, 512, 0, stream>>>(x8p, wgp, xs, wgs, act, mx);
  quant_k<<<5504, 256, 0, stream>>>(act, mx, q2p);
  gemm2_k<<<256, 512, 0, stream>>>(q2p, wdp, mx, wds, out);
}

// Round 20
// 424.885 us; speedup vs baseline: 1.0723x; 1.0200x over previous
//
#include <hip/hip_runtime.h>
#include <stdint.h>

typedef int i32x4 __attribute__((ext_vector_type(4)));
typedef unsigned short u16x8 __attribute__((ext_vector_type(8)));

#define N_TOK 2048
#define HID   4096
#define INTER 11008
#define TWOI  22016
#define KT1   64     // HID/64   k-steps for gemm1
#define KT2   172    // INTER/64 k-steps for gemm2

#define GLD16(gp, lp) __builtin_amdgcn_global_load_lds( \
    (const __attribute__((address_space(1))) void*)(gp), \
    (__attribute__((address_space(3))) void*)(lp), 16, 0, 0)
#define BAR() __builtin_amdgcn_s_barrier()
#define WVM(n) asm volatile("s_waitcnt vmcnt(" #n ")" ::: "memory")
// rule #18: lgkmcnt asm must be followed by sched_barrier(0).
#define LGKM0() do { asm volatile("s_waitcnt lgkmcnt(0)" ::: "memory"); \
                     __builtin_amdgcn_sched_barrier(0); } while (0)

__device__ __forceinline__ unsigned short f2bf(float f) {
  uint32_t u = __float_as_uint(f);
  uint32_t r = (u + 0x7fffu + ((u >> 16) & 1u)) >> 16;
  return (unsigned short)r;
}

__device__ __forceinline__ float bf2f(unsigned short b) {
  return __uint_as_float(((uint32_t)b) << 16);
}

// ---------------------------------------------------------------------------
// pack_frag: int32 [R][K] -> int8 FRAGMENT-MAJOR panels
//   [p][kt][frag f][lane l][16B]: byte(f,l) = src[p*PR + f*16 + (l&15)]
//   [kt*64 + (l>>4)*16 .. +15]. Fragment ds_read_b128 = 1024 contiguous
//   bytes -> zero bank conflicts; global_load_lds staging stays linear.
// ---------------------------------------------------------------------------
__global__ __launch_bounds__(256) void pack_frag(
    const int* __restrict__ src, uint8_t* __restrict__ dst,
    int lgPR, int KT, int K)
{
  const int u = blockIdx.x * 256 + threadIdx.x;
  const int l = u & 63;
  const int rest = u >> 6;
  const int f = rest & ((1 << (lgPR - 4)) - 1);
  const int s = rest >> (lgPR - 4);
  const int p = s / KT;
  const int kt = s - p * KT;
  const int row = (p << lgPR) + f * 16 + (l & 15);
  const int col = kt * 64 + ((l >> 4) << 4);
  const int* sp = src + (size_t)row * K + col;
  i32x4 o;
#pragma unroll
  for (int qq = 0; qq < 4; ++qq) {
    i32x4 w = *reinterpret_cast<const i32x4*>(sp + qq * 4);
    o[qq] = (w[0] & 255) | ((w[1] & 255) << 8) | ((w[2] & 255) << 16)
          | ((w[3] & 255) << 24);
  }
  *reinterpret_cast<i32x4*>(dst + (size_t)u * 16) = o;
}

// ---------------------------------------------------------------------------
// pack_gufrag: w_gateup int32 [2I][H] -> frag-major panels [86][KT1][16f][64l]
// with gate/up INTERLEAVED at fragment granularity:
//   frag 2j   = gate rows  ntB*128 + 16j .. +15
//   frag 2j+1 = up rows    INTER + ntB*128 + 16j .. +15
// -> in gemm1, acc[m][2p] (gate) and acc[m][2p+1] (up) hold the SAME
// (row, act-col) pair in registers: silu fusion needs no cross-wave exchange.
// ---------------------------------------------------------------------------
__global__ __launch_bounds__(256) void pack_gufrag(
    const int* __restrict__ src, uint8_t* __restrict__ dst)
{
  const int u = blockIdx.x * 256 + threadIdx.x;
  const int l = u & 63;
  const int rest = u >> 6;
  const int fi = rest & 15;
  const int s = rest >> 4;
  const int p = s / KT1;
  const int kt = s - p * KT1;
  const int base = p * 128 + ((fi >> 1) << 4) + (l & 15);
  const int srow = (fi & 1) ? (INTER + base) : base;
  const int col = kt * 64 + ((l >> 4) << 4);
  const int* sp = src + (size_t)srow * HID + col;
  i32x4 o;
#pragma unroll
  for (int qq = 0; qq < 4; ++qq) {
    i32x4 w = *reinterpret_cast<const i32x4*>(sp + qq * 4);
    o[qq] = (w[0] & 255) | ((w[1] & 255) << 8) | ((w[2] & 255) << 16)
          | ((w[3] & 255) << 24);
  }
  *reinterpret_cast<i32x4*>(dst + (size_t)u * 16) = o;
}

__global__ __launch_bounds__(1024) void zero_mx(float* __restrict__ mx) {
  const int i = blockIdx.x * 1024 + threadIdx.x;
  if (i < N_TOK) mx[i] = 0.0f;
}

// ---------------------------------------------------------------------------
// GEMM1 (r18-frozen K-loop): 256x256 tile, 8 waves (2Mx4N, wave 128x64),
// BK=64B, 4-slot 32KB ring (128KB LDS), distance-3, vmcnt 8/4/0, 2-phase
// K-step, fragment-major LDS (zero-conflict reads). B = interleaved gate/up
// frags. Epilogue: in-register silu(g)*u -> act bf16 [N][I]; rowmax via
// 16-lane shfl + cross-wave LDS reduce -> ONE atomicMax per row per block
// (r19 had 4/row/block -> atomic hot-spot was ~42us).
// ---------------------------------------------------------------------------
__global__ __launch_bounds__(512, 2) void gemm1_k(
    const uint8_t* __restrict__ x8p, const uint8_t* __restrict__ wgp,
    const float* __restrict__ xs, const float* __restrict__ wgs,
    unsigned short* __restrict__ act, float* __restrict__ mx)
{
  __shared__ uint8_t sm[131072];         // 4 slots x (A 16KB + B 16KB)
  const int tid = threadIdx.x;
  const int lane = tid & 63, wid = tid >> 6;
  const int wgm = wid >> 2, wgn = wid & 3;
  const int r15 = lane & 15;
  const int l16 = lane * 16;
  const int aBase = (wgm << 13) + l16;            // wgm*8192
  const int bBase = 16384 + (wgn << 12) + l16;    // 16384 + wgn*4096

  const int bid = blockIdx.x;
  const int v = (bid & 7) * 86 + (bid >> 3);   // 688 = 8*86, bijective
  const int mt = v & 7;                        // 8 M-tiles of 256
  const int ntB = v >> 3;                      // 86 act-col tiles of 128

  const uint8_t* pA = x8p + (size_t)mt  * (KT1 * 16384) + tid * 16;
  const uint8_t* pB = wgp + (size_t)ntB * (KT1 * 16384) + tid * 16;

  i32x4 acc[8][4] = {};

#define STG1(t, s) do {                                        \
    uint8_t* l = sm + (s) * 32768 + tid * 16;                  \
    const uint8_t* aa = pA + (size_t)(t) * 16384;              \
    GLD16(aa, l);                                              \
    GLD16(aa + 8192, l + 8192);                                \
    const uint8_t* bb = pB + (size_t)(t) * 16384;              \
    GLD16(bb, l + 16384);                                      \
    GLD16(bb + 8192, l + 24576);                               \
  } while (0)

  STG1(0, 0); STG1(1, 1); STG1(2, 2);    // 12 loads in flight
  WVM(8); BAR();                          // tile 0 landed; 1,2 in flight

  for (int t = 0; t < KT1; ++t) {
    const int rem = KT1 - 1 - t;
    const uint8_t* b = sm + (t & 3) * 32768;
    uint8_t* lnx = sm + ((t + 3) & 3) * 32768 + tid * 16;
    // ---------- phase A: B-frags + A-low, stage next B ----------
    i32x4 bv[4], av[4];
#pragma unroll
    for (int n = 0; n < 4; ++n)
      bv[n] = *reinterpret_cast<const i32x4*>(b + bBase + n * 1024);
#pragma unroll
    for (int m = 0; m < 4; ++m)
      av[m] = *reinterpret_cast<const i32x4*>(b + aBase + m * 1024);
    if (rem >= 3) {
      const uint8_t* bb = pB + (size_t)(t + 3) * 16384;
      GLD16(bb, lnx + 16384);
      GLD16(bb + 8192, lnx + 24576);
    }
    BAR();
    LGKM0();
    __builtin_amdgcn_s_setprio(1);
#pragma unroll
    for (int m = 0; m < 4; ++m)
#pragma unroll
      for (int n = 0; n < 4; ++n)
        acc[m][n] = __builtin_amdgcn_mfma_i32_16x16x64_i8(
            av[m], bv[n], acc[m][n], 0, 0, 0);
    __builtin_amdgcn_s_setprio(0);
    // ---------- phase B: A-high, stage next A ----------
#pragma unroll
    for (int m = 0; m < 4; ++m)
      av[m] = *reinterpret_cast<const i32x4*>(b + aBase + (m + 4) * 1024);
    if (rem >= 3) {
      const uint8_t* aa = pA + (size_t)(t + 3) * 16384;
      GLD16(aa, lnx);
      GLD16(aa + 8192, lnx + 8192);
      WVM(8);                      // tile t+1 landed; t+2,t+3 in flight
    } else if (rem == 2) { WVM(4); }
    else if (rem == 1)   { WVM(0); }
    BAR();
    LGKM0();
    __builtin_amdgcn_s_setprio(1);
#pragma unroll
    for (int m = 0; m < 4; ++m)
#pragma unroll
      for (int n = 0; n < 4; ++n)
        acc[m + 4][n] = __builtin_amdgcn_mfma_i32_16x16x64_i8(
            av[m], bv[n], acc[m + 4][n], 0, 0, 0);
    __builtin_amdgcn_s_setprio(0);
  }
#undef STG1

  __syncthreads();                        // all K-loop LDS traffic retired
  // ---- fused epilogue: silu(gate)*up in registers + rowmax ----
  // acc[m][2p] = gate(row, col p), acc[m][2p+1] = up(row, col p):
  // col = ntB*128 + wgn*32 + p*16 + r15.
  float* smred = (float*)sm;              // [4 wgn][256 rows] = 4KB (slot 0)
  const int rq = (lane >> 4) << 2;
#pragma unroll
  for (int m = 0; m < 8; ++m) {
    float am[4] = {0.f, 0.f, 0.f, 0.f};
#pragma unroll
    for (int p = 0; p < 2; ++p) {
      const int colb = ntB * 128 + (wgn << 5) + (p << 4) + r15;
      const float gsc = wgs[colb];
      const float usc = wgs[INTER + colb];
#pragma unroll
      for (int r = 0; r < 4; ++r) {
        const int rowl = (wgm << 7) + m * 16 + rq + r;
        const int grow = mt * 256 + rowl;
        const float xr = xs[grow];
        const float g  = (float)acc[m][2 * p][r] * xr * gsc;
        const float uv = (float)acc[m][2 * p + 1][r] * xr * usc;
        const float a  = g / (1.f + __expf(-g)) * uv;
        act[(size_t)grow * INTER + colb] = f2bf(a);
        am[r] = fmaxf(am[r], __builtin_fabsf(a));
      }
    }
#pragma unroll
    for (int r = 0; r < 4; ++r)
#pragma unroll
      for (int off = 1; off < 16; off <<= 1)
        am[r] = fmaxf(am[r], __shfl_xor(am[r], off, 64));
    if (r15 == 0) {
#pragma unroll
      for (int r = 0; r < 4; ++r)
        smred[wgn * 256 + (wgm << 7) + m * 16 + rq + r] = am[r];
    }
  }
  __syncthreads();
  if (tid < 256) {
    const float vmx = fmaxf(fmaxf(smred[tid], smred[256 + tid]),
                            fmaxf(smred[512 + tid], smred[768 + tid]));
    atomicMax((int*)&mx[mt * 256 + tid], __float_as_int(vmx));
  }
}

// ---------------------------------------------------------------------------
// quant: q2 = clip(rint(act * 127/mx)) -> int8 FRAGMENT-MAJOR panel
// (PR=128, 8 frags/step, 16 panels x KT2 steps). No silu recompute.
// ---------------------------------------------------------------------------
__global__ __launch_bounds__(256) void quant_k(
    const unsigned short* __restrict__ act, const float* __restrict__ mx,
    uint8_t* __restrict__ q2p)
{
  const int u = blockIdx.x * 256 + threadIdx.x;
  const int l = u & 63;
  const int rest = u >> 6;
  const int f = rest & 7;                // 8 frags (PR=128)
  const int s = rest >> 3;
  const int mt = s / KT2;
  const int t = s - mt * KT2;
  const int row = mt * 128 + f * 16 + (l & 15);
  const int col = t * 64 + ((l >> 4) << 4);
  const unsigned short* ap = act + (size_t)row * INTER + col;
  const float inv = 127.0f / fmaxf(mx[row], 1e-30f);
  u16x8 a0 = *reinterpret_cast<const u16x8*>(ap);
  u16x8 a1 = *reinterpret_cast<const u16x8*>(ap + 8);
  i32x4 o;
#pragma unroll
  for (int qq = 0; qq < 4; ++qq) {
    uint32_t d = 0;
#pragma unroll
    for (int b = 0; b < 4; ++b) {
      const int j = qq * 4 + b;
      float af = bf2f((j < 8) ? a0[j] : a1[j - 8]);
      float rr = rintf(af * inv);
      rr = fminf(fmaxf(rr, -127.f), 127.f);
      d |= ((uint32_t)((int)rr & 255)) << (8 * b);
    }
    o[qq] = (int)d;
  }
  *reinterpret_cast<i32x4*>(q2p + (size_t)u * 16) = o;
}

// ---------------------------------------------------------------------------
// GEMM2 (r18-frozen): 128x256 tile, 8 waves, BK=64B, 4-slot 24KB ring,
// distance-3, vmcnt 6/3/0, 2-phase K-step, fragment-major LDS.
// ---------------------------------------------------------------------------
__global__ __launch_bounds__(512, 2) void gemm2_k(
    const uint8_t* __restrict__ q2p, const uint8_t* __restrict__ wdp,
    const float* __restrict__ mx, const float* __restrict__ wds,
    float* __restrict__ out)
{
  __shared__ uint8_t sm[98304];
  const int tid = threadIdx.x;
  const int lane = tid & 63, wid = tid >> 6;
  const int wgm = wid >> 2, wgn = wid & 3;
  const int r15 = lane & 15;
  const int l16 = lane * 16;
  const int aBase = (wgm << 12) + l16;            // wgm*4096
  const int bBase = 8192 + (wgn << 12) + l16;     // 8192 + wgn*4096

  const int bid = blockIdx.x;
  const int v = (bid & 7) * 32 + (bid >> 3);   // XCD-chunked, bijective
  const int nt = v >> 4, mt = v & 15;

  const uint8_t* pA = q2p + (size_t)mt * (KT2 * 8192)  + tid * 16;
  const uint8_t* pB = wdp + (size_t)nt * (KT2 * 16384) + tid * 16;

  i32x4 acc[4][4] = {};

#define STG2(t, s) do {                                        \
    uint8_t* l = sm + (s) * 24576 + tid * 16;                  \
    GLD16(pA + (size_t)(t) * 8192, l);                         \
    const uint8_t* bb = pB + (size_t)(t) * 16384;              \
    GLD16(bb, l + 8192);                                       \
    GLD16(bb + 8192, l + 16384);                               \
  } while (0)

  STG2(0, 0); STG2(1, 1); STG2(2, 2);    // 9 loads in flight
  WVM(6); BAR();

  for (int t = 0; t < KT2; ++t) {
    const int rem = KT2 - 1 - t;
    const uint8_t* b = sm + (t & 3) * 24576;
    uint8_t* lnx = sm + ((t + 3) & 3) * 24576 + tid * 16;
    // ---------- phase A ----------
    i32x4 bv[4], av[2];
#pragma unroll
    for (int n = 0; n < 4; ++n)
      bv[n] = *reinterpret_cast<const i32x4*>(b + bBase + n * 1024);
#pragma unroll
    for (int m = 0; m < 2; ++m)
      av[m] = *reinterpret_cast<const i32x4*>(b + aBase + m * 1024);
    if (rem >= 3) {
      const uint8_t* bb = pB + (size_t)(t + 3) * 16384;
      GLD16(bb, lnx + 8192);
      GLD16(bb + 8192, lnx + 16384);
    }
    BAR();
    LGKM0();
    __builtin_amdgcn_s_setprio(1);
#pragma unroll
    for (int m = 0; m < 2; ++m)
#pragma unroll
      for (int n = 0; n < 4; ++n)
        acc[m][n] = __builtin_amdgcn_mfma_i32_16x16x64_i8(
            av[m], bv[n], acc[m][n], 0, 0, 0);
    __builtin_amdgcn_s_setprio(0);
    // ---------- phase B ----------
#pragma unroll
    for (int m = 0; m < 2; ++m)
      av[m] = *reinterpret_cast<const i32x4*>(b + aBase + (m + 2) * 1024);
    if (rem >= 3) {
      GLD16(pA + (size_t)(t + 3) * 8192, lnx);
      WVM(6);
    } else if (rem == 2) { WVM(3); }
    else if (rem == 1)   { WVM(0); }
    BAR();
    LGKM0();
    __builtin_amdgcn_s_setprio(1);
#pragma unroll
    for (int m = 0; m < 2; ++m)
#pragma unroll
      for (int n = 0; n < 4; ++n)
        acc[m + 2][n] = __builtin_amdgcn_mfma_i32_16x16x64_i8(
            av[m], bv[n], acc[m + 2][n], 0, 0, 0);
    __builtin_amdgcn_s_setprio(0);
  }
#undef STG2

  const int rq = (lane >> 4) << 2;
#pragma unroll
  for (int m = 0; m < 4; ++m) {
#pragma unroll
    for (int r = 0; r < 4; ++r) {
      const int rowl = (wgm << 6) + m * 16 + rq + r;
      const int grow = mt * 128 + rowl;
      const float s2 = mx[grow] * (1.0f / 127.0f);
      float* op = out + (size_t)grow * HID + nt * 256 + (wgn << 6) + r15;
      const float* wp = wds + nt * 256 + (wgn << 6) + r15;
#pragma unroll
      for (int n = 0; n < 4; ++n)
        op[n * 16] = (float)acc[m][n][r] * s2 * wp[n * 16];
    }
  }
}

// ---------------------------------------------------------------------------
extern "C" void kernel_launch(void* const* d_in, const int* in_sizes, int n_in,
                              void* d_out, int out_size, void* d_ws, size_t ws_size,
                              hipStream_t stream)
{
  const int*   x_q = (const int*)d_in[0];
  const float* xs  = (const float*)d_in[1];
  const int*   wg  = (const int*)d_in[2];
  const float* wgs = (const float*)d_in[3];
  const int*   wd  = (const int*)d_in[4];
  const float* wds = (const float*)d_in[5];
  float* out = (float*)d_out;

  uint8_t* ws = (uint8_t*)d_ws;
  uint8_t* x8p = ws;                                         //   8,388,608
  uint8_t* wgp = x8p + 8388608;                              //  90,177,536
  uint8_t* wdp = wgp + 90177536;                             //  45,088,768
  unsigned short* act = (unsigned short*)(wdp + 45088768);   //  45,088,768
  float* mx = (float*)((uint8_t*)act + 45088768);            //       8,192
  uint8_t* q2p = (uint8_t*)mx + 8192;                        //  22,544,384
  // total ~211.3 MB

  zero_mx<<<2, 1024, 0, stream>>>(mx);
  pack_frag<<<2048, 256, 0, stream>>>(x_q, x8p, 8, KT1, HID);    // A panels
  pack_gufrag<<<22016, 256, 0, stream>>>(wg, wgp);               // B1 interleaved
  pack_frag<<<11008, 256, 0, stream>>>(wd, wdp, 8, KT2, INTER);  // B2 panels

  gemm1_k<<<688, 512, 0, stream>>>(x8p, wgp, xs, wgs, act, mx);
  quant_k<<<5504, 256, 0, stream>>>(act, mx, q2p);
  gemm2_k<<<256, 512, 0, stream>>>(q2p, wdp, mx, wds, out);
}